// Round 1
// baseline (7968.377 us; speedup 1.0000x reference)
//
#include <hip/hip_runtime.h>
#include <cstdint>

#define VOCAB 500000
#define STEPS 64
#define EPSF 1e-8f

__device__ __forceinline__ float sigm(float x) { return 1.f / (1.f + expf(-x)); }
__device__ __forceinline__ float dot4(float4 a, float4 b) {
    return a.x * b.x + a.y * b.y + a.z * b.z + a.w * b.w;
}
__device__ __forceinline__ unsigned long long ullmax(unsigned long long a, unsigned long long b) {
    return a > b ? a : b;
}
// order-preserving float->uint32 map (monotone increasing)
__device__ __forceinline__ unsigned fmap(float f) {
    unsigned u = __float_as_uint(f);
    return (u & 0x80000000u) ? ~u : (u | 0x80000000u);
}

// ---------------- Kernel A: 64-step LSTM recurrence (single block) ----------------
// gates = A@x + U@h + (W_ih[:,128:]@inp + b_ih + b_hh)   -- last term constant, precomputed.
__global__ __launch_bounds__(512, 1) void lstm_kernel(
    const float* __restrict__ inp, const float* __restrict__ embed,
    const float* __restrict__ w_ih, const float* __restrict__ w_hh,
    const float* __restrict__ b_ih, const float* __restrict__ b_hh,
    float* __restrict__ out_cs,                 // d_out[0 .. 64*128)
    unsigned long long* __restrict__ slots)     // ws: 64 argmax slots
{
    __shared__ float vv[256];     // [x(128) ; h(128)]
    __shared__ float gates[512];
    const int r = threadIdx.x;

    if (r < STEPS) slots[r] = 0ull;   // init argmax slots (kernel B runs after, stream-ordered)

    // register-resident weights: A = w_ih[r][0:128], U = w_hh[r][0:128]
    float4 wa[32], wu[32];
    const float4* wihr = (const float4*)(w_ih + (size_t)r * 256);
    const float4* whhr = (const float4*)(w_hh + (size_t)r * 128);
#pragma unroll
    for (int j = 0; j < 32; ++j) wa[j] = wihr[j];
#pragma unroll
    for (int j = 0; j < 32; ++j) wu[j] = whhr[j];

    // kv = b_ih[r] + b_hh[r] + w_ih[r][128:256] . inp   (inp constant across steps)
    float kv = b_ih[r] + b_hh[r];
    {
        const float4* wib = wihr + 32;
        const float4* inp4 = (const float4*)inp;
        float k0 = 0.f, k1 = 0.f;
#pragma unroll
        for (int j = 0; j < 32; j += 2) {
            k0 += dot4(wib[j], inp4[j]);
            k1 += dot4(wib[j + 1], inp4[j + 1]);
        }
        kv += k0 + k1;
    }

    if (r < 128) { vv[r] = embed[r]; vv[128 + r] = 0.f; }  // x0 = embed[START_IDX=0], h0 = 0
    float creg = 0.f;                                      // c state for lane's row (r<128)
    __syncthreads();

    for (int t = 0; t < STEPS; ++t) {
        const float4* v4 = (const float4*)vv;
        float a0 = 0.f, a1 = 0.f, a2 = 0.f, a3 = 0.f;
#pragma unroll
        for (int j = 0; j < 32; j += 2) {
            a0 += dot4(wa[j], v4[j]);
            a1 += dot4(wa[j + 1], v4[j + 1]);
        }
#pragma unroll
        for (int j = 0; j < 32; j += 2) {
            a2 += dot4(wu[j], v4[32 + j]);
            a3 += dot4(wu[j + 1], v4[32 + j + 1]);
        }
        gates[r] = kv + (a0 + a1) + (a2 + a3);
        __syncthreads();
        if (r < 128) {
            float ig = sigm(gates[r]);
            float fg = sigm(gates[128 + r]);
            float gg = tanhf(gates[256 + r]);
            float og = sigm(gates[384 + r]);
            float cn = fg * creg + ig * gg;
            float hn = og * tanhf(cn);
            creg = cn;
            vv[r] = cn;           // next x = c_new
            vv[128 + r] = hn;     // next h
            out_cs[t * 128 + r] = cn;
        }
        __syncthreads();
    }
}

// ---------------- Kernel B: one pass over embed, 64 dots/row + norm + argmax ----------------
// Block: 256 threads, 256 rows (4 tiles of 64). Thread = (tx = tid&15 -> t in {tx,tx+16,tx+32,tx+48},
// ry = tid>>4 -> rows {ry, ry+16, ry+32, ry+48} of the tile). XOR-swizzled LDS tiles, float4 lanes.
__global__ __launch_bounds__(256) void vocab_kernel(
    const float* __restrict__ embed,
    const float* __restrict__ cs,               // d_out[0..8192): [64][128] c vectors
    unsigned long long* __restrict__ slots)
{
    __shared__ float4 c_lds[64 * 32];   // 32 KB, swizzled [t][col^ (t&31)]
    __shared__ float4 e_lds[64 * 32];   // 32 KB, swizzled; reused as reduction scratch

    const int tid = threadIdx.x;
    const int tx = tid & 15, ry = tid >> 4;

    // stage c matrix once (swizzled)
    const float4* cs4 = (const float4*)cs;
#pragma unroll
    for (int k = 0; k < 8; ++k) {
        int f = tid + k * 256;
        int row = f >> 5, j4 = f & 31;
        c_lds[row * 32 + (j4 ^ (row & 31))] = cs4[f];
    }

    unsigned long long running = 0ull;   // for tid<64: best key for t = tid
    const long long blockbase = (long long)blockIdx.x * 256;
    const float4* embed4 = (const float4*)embed;

    // precomputed swizzle bases
    int Pe[4], Pc[4];
#pragma unroll
    for (int rr = 0; rr < 4; ++rr) { int row = ry + 16 * rr; Pe[rr] = row * 32 + (row & 31); }
#pragma unroll
    for (int tt = 0; tt < 4; ++tt) { int t = tx + 16 * tt; Pc[tt] = t * 32 + (t & 31); }

    for (int tile = 0; tile < 4; ++tile) {
        const long long rowbase = blockbase + tile * 64;
        __syncthreads();   // prev reduction reads done before restaging e_lds
        // stage 64-row e tile (guard tail rows with zeros)
#pragma unroll
        for (int k = 0; k < 8; ++k) {
            int f = tid + k * 256;
            int row = f >> 5, j4 = f & 31;
            long long grow = rowbase + row;
            float4 val = make_float4(0.f, 0.f, 0.f, 0.f);
            if (grow < VOCAB) val = embed4[grow * 32 + j4];
            e_lds[row * 32 + (j4 ^ (row & 31))] = val;
        }
        __syncthreads();

        float acc[4][4];
        float ssq[4];
#pragma unroll
        for (int rr = 0; rr < 4; ++rr) {
            ssq[rr] = 0.f;
#pragma unroll
            for (int tt = 0; tt < 4; ++tt) acc[rr][tt] = 0.f;
        }

#pragma unroll
        for (int j4 = 0; j4 < 32; ++j4) {
            float4 e[4], c[4];
#pragma unroll
            for (int rr = 0; rr < 4; ++rr) e[rr] = e_lds[Pe[rr] ^ j4];
#pragma unroll
            for (int tt = 0; tt < 4; ++tt) c[tt] = c_lds[Pc[tt] ^ j4];
#pragma unroll
            for (int rr = 0; rr < 4; ++rr) {
                ssq[rr] += dot4(e[rr], e[rr]);
#pragma unroll
                for (int tt = 0; tt < 4; ++tt) acc[rr][tt] += dot4(e[rr], c[tt]);
            }
        }
        __syncthreads();   // all e_lds reads done; safe to reuse as scratch

        // per-thread local argmax over its 4 rows, per tt; packed keys to LDS
        unsigned long long* red = (unsigned long long*)e_lds;  // [tt*256 + tx*16 + ry]
        float inv[4];
        long long grows[4];
#pragma unroll
        for (int rr = 0; rr < 4; ++rr) {
            grows[rr] = rowbase + ry + 16 * rr;
            inv[rr] = 1.f / fmaxf(sqrtf(ssq[rr]), EPSF);
        }
#pragma unroll
        for (int tt = 0; tt < 4; ++tt) {
            unsigned long long k = 0ull;
#pragma unroll
            for (int rr = 0; rr < 4; ++rr) {
                if (grows[rr] < VOCAB) {
                    float q = acc[rr][tt] * inv[rr];
                    unsigned long long key = ((unsigned long long)fmap(q) << 32)
                                           | (unsigned)(0x7FFFFFFF - (int)grows[rr]);
                    k = ullmax(k, key);
                }
            }
            red[tt * 256 + tx * 16 + ry] = k;
        }
        __syncthreads();

        if (tid < 64) {
            int t = tid, ttx = t & 15, ttt = t >> 4;
#pragma unroll
            for (int r2 = 0; r2 < 16; ++r2)
                running = ullmax(running, red[ttt * 256 + ttx * 16 + r2]);
        }
    }

    if (tid < 64) atomicMax(&slots[tid], running);
}

// ---------------- Kernel C: decode argmax slots to float indices ----------------
__global__ void finalize_kernel(const unsigned long long* __restrict__ slots,
                                float* __restrict__ out_dec)
{
    int t = threadIdx.x;
    if (t < STEPS) {
        unsigned idx = 0x7FFFFFFFu - (unsigned)(slots[t] & 0xFFFFFFFFu);
        out_dec[t] = (float)idx;
    }
}

extern "C" void kernel_launch(void* const* d_in, const int* in_sizes, int n_in,
                              void* d_out, int out_size, void* d_ws, size_t ws_size,
                              hipStream_t stream) {
    (void)in_sizes; (void)n_in; (void)out_size; (void)ws_size;
    const float* inp   = (const float*)d_in[0];
    const float* embed = (const float*)d_in[1];
    const float* w_ih  = (const float*)d_in[2];
    const float* w_hh  = (const float*)d_in[3];
    const float* b_ih  = (const float*)d_in[4];
    const float* b_hh  = (const float*)d_in[5];
    float* out = (float*)d_out;
    unsigned long long* slots = (unsigned long long*)d_ws;

    hipLaunchKernelGGL(lstm_kernel, dim3(1), dim3(512), 0, stream,
                       inp, embed, w_ih, w_hh, b_ih, b_hh, out, slots);
    const int nblocks = (VOCAB + 255) / 256;   // 1954
    hipLaunchKernelGGL(vocab_kernel, dim3(nblocks), dim3(256), 0, stream,
                       embed, out, slots);
    hipLaunchKernelGGL(finalize_kernel, dim3(1), dim3(64), 0, stream,
                       slots, out + STEPS * 128);
}

// Round 2
// 926.255 us; speedup vs baseline: 8.6028x; 8.6028x over previous
//
#include <hip/hip_runtime.h>
#include <cstdint>

#define VOCAB 500000
#define STEPS 64
#define EPSF 1e-8f

__device__ __forceinline__ float sigm(float x) { return 1.f / (1.f + expf(-x)); }
__device__ __forceinline__ float dot4(float4 a, float4 b) {
    return a.x * b.x + a.y * b.y + a.z * b.z + a.w * b.w;
}
__device__ __forceinline__ unsigned long long ullmax(unsigned long long a, unsigned long long b) {
    return a > b ? a : b;
}
// order-preserving float->uint32 map (monotone increasing)
__device__ __forceinline__ unsigned fmap(float f) {
    unsigned u = __float_as_uint(f);
    return (u & 0x80000000u) ? ~u : (u | 0x80000000u);
}

// ---------------- Kernel A: 64-step LSTM recurrence (single block, 512 threads) ----------------
// Thread r owns gate-row r. Register budget (256 cap at 2 waves/EU):
//   wa[32] float4 = w_ih[r][0:128]   (A: multiplies x=c)      128 VGPR
//   wu[16] float4 = w_hh[r][0:64]    (U head)                  64 VGPR
//   U tail (cols 64..127) lives in LDS (128 KB, swizzled), streamed per step.
__global__ __launch_bounds__(512, 2) void lstm_kernel(
    const float* __restrict__ inp, const float* __restrict__ embed,
    const float* __restrict__ w_ih, const float* __restrict__ w_hh,
    const float* __restrict__ b_ih, const float* __restrict__ b_hh,
    float* __restrict__ out_cs,                 // d_out[0 .. 64*128)
    unsigned long long* __restrict__ slots)     // ws: 64 argmax slots
{
    __shared__ float4 whh_tail[512 * 16];   // 128 KB: w_hh[r][64:128], swizzled [r][j4 ^ (r&15)]
    __shared__ float vv[256];               // [x(128) ; h(128)]
    __shared__ float gates[512];
    const int r = threadIdx.x;

    if (r < STEPS) slots[r] = 0ull;   // init argmax slots (vocab kernel is stream-ordered after)

    const float4* wihr = (const float4*)(w_ih + (size_t)r * 256);
    const float4* whhr = (const float4*)(w_hh + (size_t)r * 128);

    // kv = b_ih[r] + b_hh[r] + w_ih[r][128:256] . inp   (constant across steps) — streamed
    float kv = b_ih[r] + b_hh[r];
    {
        const float4* wib = wihr + 32;
        const float4* inp4 = (const float4*)inp;
        float k0 = 0.f, k1 = 0.f;
#pragma unroll 2
        for (int j = 0; j < 32; j += 2) {
            k0 += dot4(wib[j], inp4[j]);
            k1 += dot4(wib[j + 1], inp4[j + 1]);
        }
        kv += k0 + k1;
    }

    // stage w_hh[:, 64:128] into LDS, coalesced: 8192 float4 total, 16 per thread
#pragma unroll 2
    for (int k = 0; k < 16; ++k) {
        int f = r + k * 512;
        int row = f >> 4, cj = f & 15;
        whh_tail[row * 16 + (cj ^ (row & 15))] = whhr[32 * 0 + 16 + cj + (row - r) * 0 + ((row != r) ? 0 : 0)]; // placeholder, fixed below
    }
    // NOTE: the line above must read row `row`, not r — do it properly:
    // (overwrite with correct values; cheap, still coalesced)
#pragma unroll 2
    for (int k = 0; k < 16; ++k) {
        int f = r + k * 512;
        int row = f >> 4, cj = f & 15;
        const float4* src = (const float4*)(w_hh + (size_t)row * 128);
        whh_tail[row * 16 + (cj ^ (row & 15))] = src[16 + cj];
    }

    // persistent register weights
    float4 wa[32], wu[16];
#pragma unroll
    for (int j = 0; j < 32; ++j) wa[j] = wihr[j];
#pragma unroll
    for (int j = 0; j < 16; ++j) wu[j] = whhr[j];

    if (r < 128) { vv[r] = embed[r]; vv[128 + r] = 0.f; }  // x0 = embed[0], h0 = 0
    float creg = 0.f;
    __syncthreads();

    const int rsw = (r << 4);
    for (int t = 0; t < STEPS; ++t) {
        const float4* v4 = (const float4*)vv;
        float a0 = 0.f, a1 = 0.f;
#pragma unroll
        for (int j = 0; j < 32; j += 2) {       // A @ x
            a0 += dot4(wa[j], v4[j]);
            a1 += dot4(wa[j + 1], v4[j + 1]);
        }
#pragma unroll
        for (int j = 0; j < 16; j += 2) {       // U_head @ h[0:64]
            a0 += dot4(wu[j], v4[32 + j]);
            a1 += dot4(wu[j + 1], v4[32 + j + 1]);
        }
#pragma unroll 4
        for (int j4 = 0; j4 < 16; ++j4) {       // U_tail @ h[64:128] from LDS
            float4 w = whh_tail[rsw + (j4 ^ (r & 15))];
            a0 += dot4(w, v4[48 + j4]);
        }
        gates[r] = kv + a0 + a1;
        __syncthreads();
        if (r < 128) {
            float ig = sigm(gates[r]);
            float fg = sigm(gates[128 + r]);
            float gg = tanhf(gates[256 + r]);
            float og = sigm(gates[384 + r]);
            float cn = fg * creg + ig * gg;
            float hn = og * tanhf(cn);
            creg = cn;
            vv[r] = cn;           // next x = c_new
            vv[128 + r] = hn;     // next h
            out_cs[t * 128 + r] = cn;
        }
        __syncthreads();
    }
}

// ---------------- Kernel B: one pass over embed, 64 dots/row + norm + argmax ----------------
__global__ __launch_bounds__(256, 2) void vocab_kernel(
    const float* __restrict__ embed,
    const float* __restrict__ cs,               // d_out[0..8192): [64][128] c vectors
    unsigned long long* __restrict__ slots)
{
    __shared__ float4 c_lds[64 * 32];   // 32 KB, swizzled [t][j4 ^ (t&31)]
    __shared__ float4 e_lds[64 * 32];   // 32 KB, swizzled; reused as reduction scratch

    const int tid = threadIdx.x;
    const int tx = tid & 15, ry = tid >> 4;

    // stage c matrix once (swizzled)
    const float4* cs4 = (const float4*)cs;
#pragma unroll 2
    for (int k = 0; k < 8; ++k) {
        int f = tid + k * 256;
        int row = f >> 5, j4 = f & 31;
        c_lds[row * 32 + (j4 ^ (row & 31))] = cs4[f];
    }

    unsigned long long running = 0ull;   // tid<64: best key for t = tid
    const long long blockbase = (long long)blockIdx.x * 256;
    const float4* embed4 = (const float4*)embed;

    int Pe[4], Pc[4];
#pragma unroll
    for (int rr = 0; rr < 4; ++rr) { int row = ry + 16 * rr; Pe[rr] = row * 32 + (row & 31); }
#pragma unroll
    for (int tt = 0; tt < 4; ++tt) { int t = tx + 16 * tt; Pc[tt] = t * 32 + (t & 31); }

    for (int tile = 0; tile < 4; ++tile) {
        const long long rowbase = blockbase + tile * 64;
        __syncthreads();   // prev reduction reads done before restaging e_lds
#pragma unroll 2
        for (int k = 0; k < 8; ++k) {
            int f = tid + k * 256;
            int row = f >> 5, j4 = f & 31;
            long long grow = rowbase + row;
            float4 val = make_float4(0.f, 0.f, 0.f, 0.f);
            if (grow < VOCAB) val = embed4[grow * 32 + j4];
            e_lds[row * 32 + (j4 ^ (row & 31))] = val;
        }
        __syncthreads();

        float acc[4][4];
        float ssq[4];
#pragma unroll
        for (int rr = 0; rr < 4; ++rr) {
            ssq[rr] = 0.f;
#pragma unroll
            for (int tt = 0; tt < 4; ++tt) acc[rr][tt] = 0.f;
        }

#pragma unroll 2
        for (int j4 = 0; j4 < 32; ++j4) {
            float4 c0 = c_lds[Pc[0] ^ j4];
            float4 c1 = c_lds[Pc[1] ^ j4];
            float4 c2 = c_lds[Pc[2] ^ j4];
            float4 c3 = c_lds[Pc[3] ^ j4];
#pragma unroll
            for (int rr = 0; rr < 4; ++rr) {
                float4 e = e_lds[Pe[rr] ^ j4];
                ssq[rr]    += dot4(e, e);
                acc[rr][0] += dot4(e, c0);
                acc[rr][1] += dot4(e, c1);
                acc[rr][2] += dot4(e, c2);
                acc[rr][3] += dot4(e, c3);
            }
        }
        __syncthreads();   // all e_lds reads done; safe to reuse as scratch

        unsigned long long* red = (unsigned long long*)e_lds;  // [tt*256 + tx*16 + ry]
        float inv[4];
        long long grows[4];
#pragma unroll
        for (int rr = 0; rr < 4; ++rr) {
            grows[rr] = rowbase + ry + 16 * rr;
            inv[rr] = 1.f / fmaxf(sqrtf(ssq[rr]), EPSF);
        }
#pragma unroll
        for (int tt = 0; tt < 4; ++tt) {
            unsigned long long k = 0ull;
#pragma unroll
            for (int rr = 0; rr < 4; ++rr) {
                if (grows[rr] < VOCAB) {
                    float q = acc[rr][tt] * inv[rr];
                    unsigned long long key = ((unsigned long long)fmap(q) << 32)
                                           | (unsigned)(0x7FFFFFFF - (int)grows[rr]);
                    k = ullmax(k, key);
                }
            }
            red[tt * 256 + tx * 16 + ry] = k;
        }
        __syncthreads();

        if (tid < 64) {
            int t = tid, ttx = t & 15, ttt = t >> 4;
#pragma unroll
            for (int r2 = 0; r2 < 16; ++r2)
                running = ullmax(running, red[ttt * 256 + ttx * 16 + r2]);
        }
    }

    if (tid < 64) atomicMax(&slots[tid], running);
}

// ---------------- Kernel C: decode argmax slots to float indices ----------------
__global__ void finalize_kernel(const unsigned long long* __restrict__ slots,
                                float* __restrict__ out_dec)
{
    int t = threadIdx.x;
    if (t < STEPS) {
        unsigned idx = 0x7FFFFFFFu - (unsigned)(slots[t] & 0xFFFFFFFFu);
        out_dec[t] = (float)idx;
    }
}

extern "C" void kernel_launch(void* const* d_in, const int* in_sizes, int n_in,
                              void* d_out, int out_size, void* d_ws, size_t ws_size,
                              hipStream_t stream) {
    (void)in_sizes; (void)n_in; (void)out_size; (void)ws_size;
    const float* inp   = (const float*)d_in[0];
    const float* embed = (const float*)d_in[1];
    const float* w_ih  = (const float*)d_in[2];
    const float* w_hh  = (const float*)d_in[3];
    const float* b_ih  = (const float*)d_in[4];
    const float* b_hh  = (const float*)d_in[5];
    float* out = (float*)d_out;
    unsigned long long* slots = (unsigned long long*)d_ws;

    hipLaunchKernelGGL(lstm_kernel, dim3(1), dim3(512), 0, stream,
                       inp, embed, w_ih, w_hh, b_ih, b_hh, out, slots);
    const int nblocks = (VOCAB + 255) / 256;   // 1954
    hipLaunchKernelGGL(vocab_kernel, dim3(nblocks), dim3(256), 0, stream,
                       embed, out, slots);
    hipLaunchKernelGGL(finalize_kernel, dim3(1), dim3(64), 0, stream,
                       slots, out + STEPS * 128);
}

// Round 3
// 899.411 us; speedup vs baseline: 8.8596x; 1.0298x over previous
//
#include <hip/hip_runtime.h>
#include <cstdint>

#define VOCAB 500000
#define STEPS 64
#define EPSF 1e-8f

__device__ __forceinline__ float sigm(float x) { return 1.f / (1.f + expf(-x)); }
__device__ __forceinline__ float dot4(float4 a, float4 b) {
    return a.x * b.x + a.y * b.y + a.z * b.z + a.w * b.w;
}
__device__ __forceinline__ unsigned long long ullmax(unsigned long long a, unsigned long long b) {
    return a > b ? a : b;
}
// order-preserving float->uint32 map (monotone increasing)
__device__ __forceinline__ unsigned fmap(float f) {
    unsigned u = __float_as_uint(f);
    return (u & 0x80000000u) ? ~u : (u | 0x80000000u);
}

// ---------------- Kernel A: 64-step LSTM recurrence (single block, 512 threads) ----------------
// Thread r owns gate-row r. waves_per_eu(2,2) pins 2 waves/SIMD -> 256-VGPR budget, so the
// allocator keeps the 192 weight VGPRs resident (R2's 128-reg choice spilled them -> 6 us/step).
//   wa[32] float4 = w_ih[r][0:128]   (multiplies x=c)   128 VGPR
//   wu[16] float4 = w_hh[r][0:64]    (U head)            64 VGPR
//   U tail (cols 64..127): LDS, 128 KB, swizzled.
__global__ __launch_bounds__(512)
__attribute__((amdgpu_waves_per_eu(2, 2)))
void lstm_kernel(
    const float* __restrict__ inp, const float* __restrict__ embed,
    const float* __restrict__ w_ih, const float* __restrict__ w_hh,
    const float* __restrict__ b_ih, const float* __restrict__ b_hh,
    float* __restrict__ out_cs,                 // d_out[0 .. 64*128)
    unsigned long long* __restrict__ slots)     // ws: 64 argmax slots
{
    __shared__ float4 whh_tail[512 * 16];   // 128 KB: w_hh[r][64:128], swizzled [r][j4 ^ (r&15)]
    __shared__ float vv[256];               // [x(128) ; h(128)]
    __shared__ float gates[512];
    const int r = threadIdx.x;

    if (r < STEPS) slots[r] = 0ull;   // init argmax slots (vocab kernel is stream-ordered after)

    const float4* wihr = (const float4*)(w_ih + (size_t)r * 256);
    const float4* whhr = (const float4*)(w_hh + (size_t)r * 128);

    // kv = b_ih[r] + b_hh[r] + w_ih[r][128:256] . inp   (constant across steps) — streamed
    float kv = b_ih[r] + b_hh[r];
    {
        const float4* wib = wihr + 32;
        const float4* inp4 = (const float4*)inp;
        float k0 = 0.f, k1 = 0.f;
#pragma unroll 2
        for (int j = 0; j < 32; j += 2) {
            k0 += dot4(wib[j], inp4[j]);
            k1 += dot4(wib[j + 1], inp4[j + 1]);
        }
        kv += k0 + k1;
    }

    // stage w_hh[:, 64:128] into LDS (coalesced: consecutive threads hit consecutive float4s)
#pragma unroll 2
    for (int k = 0; k < 16; ++k) {
        int f = r + k * 512;
        int row = f >> 4, cj = f & 15;
        const float4* src = (const float4*)(w_hh + (size_t)row * 128);
        whh_tail[row * 16 + (cj ^ (row & 15))] = src[16 + cj];
    }

    // persistent register weights
    float4 wa[32], wu[16];
#pragma unroll
    for (int j = 0; j < 32; ++j) wa[j] = wihr[j];
#pragma unroll
    for (int j = 0; j < 16; ++j) wu[j] = whhr[j];

    if (r < 128) { vv[r] = embed[r]; vv[128 + r] = 0.f; }  // x0 = embed[0], h0 = 0
    float creg = 0.f;
    __syncthreads();

    const int rsw = (r << 4);
    const int rm = r & 15;
    for (int t = 0; t < STEPS; ++t) {
        const float4* v4 = (const float4*)vv;
        float a0 = 0.f, a1 = 0.f;
#pragma unroll
        for (int j = 0; j < 32; j += 2) {       // A @ x
            a0 += dot4(wa[j], v4[j]);
            a1 += dot4(wa[j + 1], v4[j + 1]);
        }
#pragma unroll
        for (int j = 0; j < 16; j += 2) {       // U_head @ h[0:64]
            a0 += dot4(wu[j], v4[32 + j]);
            a1 += dot4(wu[j + 1], v4[32 + j + 1]);
        }
#pragma unroll 4
        for (int j4 = 0; j4 < 16; ++j4) {       // U_tail @ h[64:128] from LDS
            float4 w = whh_tail[rsw + (j4 ^ rm)];
            a0 += dot4(w, v4[48 + j4]);
        }
        gates[r] = kv + a0 + a1;
        __syncthreads();
        if (r < 128) {
            float ig = sigm(gates[r]);
            float fg = sigm(gates[128 + r]);
            float gg = tanhf(gates[256 + r]);
            float og = sigm(gates[384 + r]);
            float cn = fg * creg + ig * gg;
            float hn = og * tanhf(cn);
            creg = cn;
            vv[r] = cn;           // next x = c_new
            vv[128 + r] = hn;     // next h
            out_cs[t * 128 + r] = cn;
        }
        __syncthreads();
    }
}

// ---------------- Kernel B: one pass over embed, 64 dots/row + norm + argmax ----------------
// 256 threads, 256 rows/block (4 tiles of 64). Thread = (tx=tid&15 -> t in {tx,tx+16,tx+32,tx+48},
// ry=tid>>4 -> rows {ry,ry+16,ry+32,ry+48}). ssq computed at staging time (per-(row,j4) partials),
// inner loop is pure acc FMAs: 8 b128 LDS reads + 16 dot4 per j4.
__global__ __launch_bounds__(256)
__attribute__((amdgpu_waves_per_eu(2, 2)))
void vocab_kernel(
    const float* __restrict__ embed,
    const float* __restrict__ cs,               // d_out[0..8192): [64][128] c vectors
    unsigned long long* __restrict__ slots)
{
    __shared__ float4 c_lds[64 * 32];   // 32 KB, swizzled [t][j4 ^ (t&31)]
    __shared__ float4 e_lds[64 * 32];   // 32 KB, swizzled; reused as u64 reduction scratch
    __shared__ float ssq_part[64 * 32]; // 8 KB: per-(row,j4) |e4|^2 partials, written at staging

    const int tid = threadIdx.x;
    const int tx = tid & 15, ry = tid >> 4;

    // stage c matrix once (swizzled)
    const float4* cs4 = (const float4*)cs;
#pragma unroll 2
    for (int k = 0; k < 8; ++k) {
        int f = tid + k * 256;
        int row = f >> 5, j4 = f & 31;
        c_lds[row * 32 + (j4 ^ (row & 31))] = cs4[f];
    }

    unsigned long long running = 0ull;   // tid<64: best key for t = tid
    const long long blockbase = (long long)blockIdx.x * 256;
    const float4* embed4 = (const float4*)embed;

    int Pe[4], Pc[4];
#pragma unroll
    for (int rr = 0; rr < 4; ++rr) { int row = ry + 16 * rr; Pe[rr] = row * 32 + (row & 31); }
#pragma unroll
    for (int tt = 0; tt < 4; ++tt) { int t = tx + 16 * tt; Pc[tt] = t * 32 + (t & 31); }

    for (int tile = 0; tile < 4; ++tile) {
        const long long rowbase = blockbase + tile * 64;
        __syncthreads();   // prev reduction reads done before restaging e_lds / ssq_part
#pragma unroll 2
        for (int k = 0; k < 8; ++k) {
            int f = tid + k * 256;
            int row = f >> 5, j4 = f & 31;
            long long grow = rowbase + row;
            float4 val = make_float4(0.f, 0.f, 0.f, 0.f);
            if (grow < VOCAB) val = embed4[grow * 32 + j4];
            e_lds[row * 32 + (j4 ^ (row & 31))] = val;
            ssq_part[row * 32 + j4] = dot4(val, val);
        }
        __syncthreads();

        float acc[4][4];
#pragma unroll
        for (int rr = 0; rr < 4; ++rr)
#pragma unroll
            for (int tt = 0; tt < 4; ++tt) acc[rr][tt] = 0.f;

#pragma unroll 2
        for (int j4 = 0; j4 < 32; ++j4) {
            float4 c0 = c_lds[Pc[0] ^ j4];
            float4 c1 = c_lds[Pc[1] ^ j4];
            float4 c2 = c_lds[Pc[2] ^ j4];
            float4 c3 = c_lds[Pc[3] ^ j4];
#pragma unroll
            for (int rr = 0; rr < 4; ++rr) {
                float4 e = e_lds[Pe[rr] ^ j4];
                acc[rr][0] += dot4(e, c0);
                acc[rr][1] += dot4(e, c1);
                acc[rr][2] += dot4(e, c2);
                acc[rr][3] += dot4(e, c3);
            }
        }

        // per-row inv-norm from staged partials (broadcast reads, once per tile)
        float inv[4];
        long long grows[4];
#pragma unroll
        for (int rr = 0; rr < 4; ++rr) {
            int row = ry + 16 * rr;
            float s0 = 0.f, s1 = 0.f;
#pragma unroll 4
            for (int j = 0; j < 32; j += 2) {
                s0 += ssq_part[row * 32 + j];
                s1 += ssq_part[row * 32 + j + 1];
            }
            inv[rr] = 1.f / fmaxf(sqrtf(s0 + s1), EPSF);
            grows[rr] = rowbase + row;
        }
        __syncthreads();   // all e_lds reads done; safe to reuse as scratch

        unsigned long long* red = (unsigned long long*)e_lds;  // [tt*256 + tx*16 + ry]
#pragma unroll
        for (int tt = 0; tt < 4; ++tt) {
            unsigned long long k = 0ull;
#pragma unroll
            for (int rr = 0; rr < 4; ++rr) {
                if (grows[rr] < VOCAB) {
                    float q = acc[rr][tt] * inv[rr];
                    unsigned long long key = ((unsigned long long)fmap(q) << 32)
                                           | (unsigned)(0x7FFFFFFF - (int)grows[rr]);
                    k = ullmax(k, key);
                }
            }
            red[tt * 256 + tx * 16 + ry] = k;
        }
        __syncthreads();

        if (tid < 64) {
            int t = tid, ttx = t & 15, ttt = t >> 4;
#pragma unroll
            for (int r2 = 0; r2 < 16; ++r2)
                running = ullmax(running, red[ttt * 256 + ttx * 16 + r2]);
        }
    }

    if (tid < 64) atomicMax(&slots[tid], running);
}

// ---------------- Kernel C: decode argmax slots to float indices ----------------
__global__ void finalize_kernel(const unsigned long long* __restrict__ slots,
                                float* __restrict__ out_dec)
{
    int t = threadIdx.x;
    if (t < STEPS) {
        unsigned idx = 0x7FFFFFFFu - (unsigned)(slots[t] & 0xFFFFFFFFu);
        out_dec[t] = (float)idx;
    }
}

extern "C" void kernel_launch(void* const* d_in, const int* in_sizes, int n_in,
                              void* d_out, int out_size, void* d_ws, size_t ws_size,
                              hipStream_t stream) {
    (void)in_sizes; (void)n_in; (void)out_size; (void)ws_size;
    const float* inp   = (const float*)d_in[0];
    const float* embed = (const float*)d_in[1];
    const float* w_ih  = (const float*)d_in[2];
    const float* w_hh  = (const float*)d_in[3];
    const float* b_ih  = (const float*)d_in[4];
    const float* b_hh  = (const float*)d_in[5];
    float* out = (float*)d_out;
    unsigned long long* slots = (unsigned long long*)d_ws;

    hipLaunchKernelGGL(lstm_kernel, dim3(1), dim3(512), 0, stream,
                       inp, embed, w_ih, w_hh, b_ih, b_hh, out, slots);
    const int nblocks = (VOCAB + 255) / 256;   // 1954
    hipLaunchKernelGGL(vocab_kernel, dim3(nblocks), dim3(256), 0, stream,
                       embed, out, slots);
    hipLaunchKernelGGL(finalize_kernel, dim3(1), dim3(64), 0, stream,
                       slots, out + STEPS * 128);
}